// Round 9
// baseline (201.047 us; speedup 1.0000x reference)
//
#include <hip/hip_runtime.h>
#include <hip/hip_cooperative_groups.h>
#include <math.h>

namespace cg = cooperative_groups;

#define BB 256       // batch
#define CC 1024      // channels
#define CC4 (CC/4)   // row length in float4
#define MARGIN 0.5f
#define NSL 8        // c-slices (chunks of 128)
#define LDSM 68      // mega-kernel LDS row stride (64-c sub-chunk, 16B aligned)
#define LDST 132     // fallback pass kernels' LDS row stride (128-c chunk)

// ws (floats): mcsq[256*1024] | S_part[8*65536] | THR[65536] |
//              IDS_part[8*65536] | MD_part[8*65536] | acc | cnt
// (THR used only by the fallback path; mega folds thr inline.)

// ===========================================================================
// Cooperative mega kernel: 512 blocks x 256 threads, 34.8 KB LDS (4 blk/CU
// capacity -> co-residency validator has margin). Phases split by grid.sync:
//   P1: S_part[cc] slice (32i x 32j x 128c; two 64-c halves in xs/ms);
//       blocks 448..511 also compute mcsq (1 row/wave).
//   P2: IDS/MD slices; thr folded inline from the 8 S_part slices.
//   P3: blocks 0..63 fold rows, butterfly, atomic mean; elected publish.
// ===========================================================================
__global__ __launch_bounds__(256, 2) void mega_kernel(
    const float* __restrict__ x, const int* __restrict__ targets,
    const int* __restrict__ subs, const int* __restrict__ m_count_p,
    float* __restrict__ mcsq, float* __restrict__ S_part,
    float* __restrict__ IDS_part, float* __restrict__ MD_part,
    float* __restrict__ acc, unsigned int* __restrict__ cnt_g,
    float* __restrict__ out)
{
    cg::grid_group grid = cg::this_grid();
    __shared__ float xs[64 * LDSM];
    __shared__ float ms[64 * LDSM];
    const int b = blockIdx.x;
    const int l = threadIdx.x;
    const int cc = b & 7, jt = (b >> 3) & 7, it = b >> 6;
    const float4* x4 = (const float4*)x;
    const int li = l >> 4, lj = l & 15;
    const int gi0 = it * 32 + 2 * li, gj0 = jt * 32 + 2 * lj;

    if (b == 0 && l == 0) { *acc = 0.f; *cnt_g = 0u; }

    // ================= phase 1: S_part slice =================
    #pragma unroll
    for (int k = 0; k < 4; ++k) {
        const int idx = l + 256 * k;       // 0..1023
        const int row = idx >> 4;          // 0..63
        const int c4  = idx & 15;          // 0..15
        const int grow = (row < 32) ? (it * 32 + row) : (jt * 32 + row - 32);
        *(float4*)&xs[row * LDSM + c4 * 4] = x4[grow * CC4 + cc * 32 + c4];
        *(float4*)&ms[row * LDSM + c4 * 4] = x4[grow * CC4 + cc * 32 + 16 + c4];
    }
    __syncthreads();
    {
        float s00 = 0.f, s01 = 0.f, s10 = 0.f, s11 = 0.f;
        #pragma unroll
        for (int h = 0; h < 2; ++h) {
            const float* buf = h ? ms : xs;
            const float4* pi0 = (const float4*)&buf[(2 * li) * LDSM];
            const float4* pi1 = (const float4*)&buf[(2 * li + 1) * LDSM];
            const float4* pj0 = (const float4*)&buf[(32 + 2 * lj) * LDSM];
            const float4* pj1 = (const float4*)&buf[(32 + 2 * lj + 1) * LDSM];
            #pragma unroll 8
            for (int q = 0; q < 16; ++q) {
                const float4 a0 = pi0[q], a1 = pi1[q], b0 = pj0[q], b1 = pj1[q];
                s00 += fabsf(a0.x - b0.x) + fabsf(a0.y - b0.y) + fabsf(a0.z - b0.z) + fabsf(a0.w - b0.w);
                s01 += fabsf(a0.x - b1.x) + fabsf(a0.y - b1.y) + fabsf(a0.z - b1.z) + fabsf(a0.w - b1.w);
                s10 += fabsf(a1.x - b0.x) + fabsf(a1.y - b0.y) + fabsf(a1.z - b0.z) + fabsf(a1.w - b0.w);
                s11 += fabsf(a1.x - b1.x) + fabsf(a1.y - b1.y) + fabsf(a1.z - b1.z) + fabsf(a1.w - b1.w);
            }
        }
        float* Sp = S_part + cc * (BB * BB);
        Sp[gi0 * BB + gj0]           = s00;
        Sp[gi0 * BB + gj0 + 1]       = s01;
        Sp[(gi0 + 1) * BB + gj0]     = s10;
        Sp[(gi0 + 1) * BB + gj0 + 1] = s11;
    }

    // mcsq on blocks 448..511: row i = (b-448)*4 + wave
    if (b >= 448) {
        const int lane = l & 63;
        const int i = (b - 448) * 4 + (l >> 6);
        const int ti = targets[i], si = subs[i];
        int mc = *m_count_p;
        if (mc > 8) mc = 8;

        unsigned long long masks[4];
        #pragma unroll
        for (int q = 0; q < 4; ++q) {
            const int j = q * 64 + lane;
            masks[q] = __ballot(targets[j] == ti && subs[j] == si);
        }
        int idx[8];
        int cnt = 0;
        for (int q = 0; q < 4 && cnt < mc; ++q) {
            unsigned long long m = masks[q];
            while (m && cnt < mc) {
                const int bb2 = __ffsll(m) - 1;
                idx[cnt++] = q * 64 + bb2;
                m &= m - 1;
            }
        }
        for (int q = 0; q < 4 && cnt < mc; ++q) {   // stable-argsort padding
            unsigned long long m = ~masks[q];
            while (m && cnt < mc) {
                const int bb2 = __ffsll(m) - 1;
                idx[cnt++] = q * 64 + bb2;
                m &= m - 1;
            }
        }

        float4 xi[4];
        #pragma unroll
        for (int t = 0; t < 4; ++t) xi[t] = x4[(long)i * CC4 + lane + 64 * t];
        float4 c4v[4];
        #pragma unroll
        for (int t = 0; t < 4; ++t) c4v[t] = make_float4(0.f, 0.f, 0.f, 0.f);

        for (int k = 0; k < cnt; ++k) {
            float4 ad[4];
            float s = 0.f;
            #pragma unroll
            for (int t = 0; t < 4; ++t) {
                const float4 xj = x4[(long)idx[k] * CC4 + lane + 64 * t];
                ad[t].x = fabsf(xi[t].x - xj.x);
                ad[t].y = fabsf(xi[t].y - xj.y);
                ad[t].z = fabsf(xi[t].z - xj.z);
                ad[t].w = fabsf(xi[t].w - xj.w);
                s += ad[t].x + ad[t].y + ad[t].z + ad[t].w;
            }
            #pragma unroll
            for (int off = 32; off > 0; off >>= 1) s += __shfl_xor(s, off, 64);
            const float thr = s * (MARGIN / CC);
            #pragma unroll
            for (int t = 0; t < 4; ++t) {
                c4v[t].x += (ad[t].x < thr) ? 1.f : 0.f;
                c4v[t].y += (ad[t].y < thr) ? 1.f : 0.f;
                c4v[t].z += (ad[t].z < thr) ? 1.f : 0.f;
                c4v[t].w += (ad[t].w < thr) ? 1.f : 0.f;
            }
        }
        float4* mout = (float4*)mcsq;
        #pragma unroll
        for (int t = 0; t < 4; ++t) {
            float4 o;
            o.x = c4v[t].x * c4v[t].x;
            o.y = c4v[t].y * c4v[t].y;
            o.z = c4v[t].z * c4v[t].z;
            o.w = c4v[t].w * c4v[t].w;
            mout[(long)i * CC4 + lane + 64 * t] = o;
        }
    }

    grid.sync();

    // ================= phase 2: IDS/MD slices =================
    {
        // fold thr from the 8 S_part slices (global, no LDS dependency)
        float t00 = 0.f, t01 = 0.f, t10 = 0.f, t11 = 0.f;
        #pragma unroll
        for (int s = 0; s < NSL; ++s) {
            const float* Sp = S_part + s * (BB * BB);
            t00 += Sp[gi0 * BB + gj0];
            t01 += Sp[gi0 * BB + gj0 + 1];
            t10 += Sp[(gi0 + 1) * BB + gj0];
            t11 += Sp[(gi0 + 1) * BB + gj0 + 1];
        }
        t00 *= (MARGIN / CC); t01 *= (MARGIN / CC);
        t10 *= (MARGIN / CC); t11 *= (MARGIN / CC);

        const float4* m4 = (const float4*)mcsq;
        float i00 = 0.f, i01 = 0.f, i10 = 0.f, i11 = 0.f;
        float m00 = 0.f, m01 = 0.f, m10 = 0.f, m11 = 0.f;
        for (int h = 0; h < 2; ++h) {
            __syncthreads();   // protect buffers from previous use
            #pragma unroll
            for (int k = 0; k < 4; ++k) {
                const int idx = l + 256 * k;
                const int row = idx >> 4;
                const int c4  = idx & 15;
                const int grow = (row < 32) ? (it * 32 + row) : (jt * 32 + row - 32);
                *(float4*)&xs[row * LDSM + c4 * 4] = x4[grow * CC4 + cc * 32 + h * 16 + c4];
                *(float4*)&ms[row * LDSM + c4 * 4] = m4[grow * CC4 + cc * 32 + h * 16 + c4];
            }
            __syncthreads();
            const float4* pi0 = (const float4*)&xs[(2 * li) * LDSM];
            const float4* pi1 = (const float4*)&xs[(2 * li + 1) * LDSM];
            const float4* pj0 = (const float4*)&xs[(32 + 2 * lj) * LDSM];
            const float4* pj1 = (const float4*)&xs[(32 + 2 * lj + 1) * LDSM];
            const float4* qi0 = (const float4*)&ms[(2 * li) * LDSM];
            const float4* qi1 = (const float4*)&ms[(2 * li + 1) * LDSM];
            const float4* qj0 = (const float4*)&ms[(32 + 2 * lj) * LDSM];
            const float4* qj1 = (const float4*)&ms[(32 + 2 * lj + 1) * LDSM];
            #pragma unroll 4
            for (int q = 0; q < 16; ++q) {
                const float4 a0 = pi0[q], a1 = pi1[q], b0 = pj0[q], b1 = pj1[q];
                const float4 wa0 = qi0[q], wa1 = qi1[q], wb0 = qj0[q], wb1 = qj1[q];
                #pragma unroll
                for (int u = 0; u < 4; ++u) {
                    const float xa0 = (&a0.x)[u], xa1 = (&a1.x)[u];
                    const float xb0 = (&b0.x)[u], xb1 = (&b1.x)[u];
                    const float va0 = (&wa0.x)[u], va1 = (&wa1.x)[u];
                    const float vb0 = (&wb0.x)[u], vb1 = (&wb1.x)[u];
                    float d, qq;
                    d = xa0 - xb0; qq = d * d; i00 += (fabsf(d) < t00) ? qq : 0.f; m00 += qq * va0 * vb0;
                    d = xa0 - xb1; qq = d * d; i01 += (fabsf(d) < t01) ? qq : 0.f; m01 += qq * va0 * vb1;
                    d = xa1 - xb0; qq = d * d; i10 += (fabsf(d) < t10) ? qq : 0.f; m10 += qq * va1 * vb0;
                    d = xa1 - xb1; qq = d * d; i11 += (fabsf(d) < t11) ? qq : 0.f; m11 += qq * va1 * vb1;
                }
            }
        }
        float* Ip = IDS_part + cc * (BB * BB);
        float* Mp = MD_part  + cc * (BB * BB);
        Ip[gi0 * BB + gj0]           = i00;
        Ip[gi0 * BB + gj0 + 1]       = i01;
        Ip[(gi0 + 1) * BB + gj0]     = i10;
        Ip[(gi0 + 1) * BB + gj0 + 1] = i11;
        Mp[gi0 * BB + gj0]           = m00;
        Mp[gi0 * BB + gj0 + 1]       = m01;
        Mp[(gi0 + 1) * BB + gj0]     = m10;
        Mp[(gi0 + 1) * BB + gj0 + 1] = m11;
    }

    grid.sync();

    // ================= phase 3: final fold (blocks 0..63) =================
    if (b < 64) {
        const int lane = l & 63;
        const int i = b * 4 + (l >> 6);
        const int ti = targets[i];

        float4 idv = make_float4(0.f, 0.f, 0.f, 0.f);
        float4 mdv = make_float4(0.f, 0.f, 0.f, 0.f);
        #pragma unroll
        for (int s = 0; s < NSL; ++s) {
            const float4 a = ((const float4*)(IDS_part + s * (BB * BB) + i * BB))[lane];
            const float4 c = ((const float4*)(MD_part  + s * (BB * BB) + i * BB))[lane];
            idv.x += a.x; idv.y += a.y; idv.z += a.z; idv.w += a.w;
            mdv.x += c.x; mdv.y += c.y; mdv.z += c.z; mdv.w += c.w;
        }
        const int4 tjv = ((const int4*)targets)[lane];

        float mx, mn;
        mx =           sqrtf(fmaxf(mdv.x, 1e-12f));
        mx = fmaxf(mx, sqrtf(fmaxf(mdv.y, 1e-12f)));
        mx = fmaxf(mx, sqrtf(fmaxf(mdv.z, 1e-12f)));
        mx = fmaxf(mx, sqrtf(fmaxf(mdv.w, 1e-12f)));
        mn =           (tjv.x != ti) ? sqrtf(fmaxf(idv.x, 1e-12f)) : INFINITY;
        mn = fminf(mn, (tjv.y != ti) ? sqrtf(fmaxf(idv.y, 1e-12f)) : INFINITY);
        mn = fminf(mn, (tjv.z != ti) ? sqrtf(fmaxf(idv.z, 1e-12f)) : INFINITY);
        mn = fminf(mn, (tjv.w != ti) ? sqrtf(fmaxf(idv.w, 1e-12f)) : INFINITY);

        #pragma unroll
        for (int off = 32; off > 0; off >>= 1) {
            mx = fmaxf(mx, __shfl_xor(mx, off, 64));
            mn = fminf(mn, __shfl_xor(mn, off, 64));
        }
        if (lane == 0) {
            const float per = fmaxf(mx * 10.f - mn, 0.f);
            atomicAdd(acc, per * (1.0f / BB));
            __threadfence();
            const unsigned int old = atomicAdd(cnt_g, 1u);
            if (old == BB - 1) {
                __threadfence();
                out[0] = atomicAdd(acc, 0.0f);
            }
        }
    }
}

// ===========================================================================
// Fallback path: the R7 5-kernel chain (known correct at 99.3 us).
// ===========================================================================
__global__ __launch_bounds__(64) void mcsq_kernel(
    const float* __restrict__ x, const int* __restrict__ targets,
    const int* __restrict__ subs, const int* __restrict__ m_count_p,
    float* __restrict__ mcsq, float* __restrict__ acc,
    unsigned int* __restrict__ cnt_g)
{
    const int i = blockIdx.x;
    const int lane = threadIdx.x;
    if (i == 0 && lane == 0) { *acc = 0.f; *cnt_g = 0u; }
    const int ti = targets[i], si = subs[i];
    int mc = *m_count_p;
    if (mc > 8) mc = 8;

    unsigned long long masks[4];
    #pragma unroll
    for (int q = 0; q < 4; ++q) {
        const int j = q * 64 + lane;
        masks[q] = __ballot(targets[j] == ti && subs[j] == si);
    }
    int idx[8];
    int cnt = 0;
    for (int q = 0; q < 4 && cnt < mc; ++q) {
        unsigned long long m = masks[q];
        while (m && cnt < mc) {
            const int b = __ffsll(m) - 1;
            idx[cnt++] = q * 64 + b;
            m &= m - 1;
        }
    }
    for (int q = 0; q < 4 && cnt < mc; ++q) {
        unsigned long long m = ~masks[q];
        while (m && cnt < mc) {
            const int b = __ffsll(m) - 1;
            idx[cnt++] = q * 64 + b;
            m &= m - 1;
        }
    }

    const float4* x4 = (const float4*)x;
    float4 xi[4];
    #pragma unroll
    for (int t = 0; t < 4; ++t) xi[t] = x4[(long)i * CC4 + lane + 64 * t];
    float4 c4[4];
    #pragma unroll
    for (int t = 0; t < 4; ++t) c4[t] = make_float4(0.f, 0.f, 0.f, 0.f);

    for (int k = 0; k < cnt; ++k) {
        float4 ad[4];
        float s = 0.f;
        #pragma unroll
        for (int t = 0; t < 4; ++t) {
            const float4 xj = x4[(long)idx[k] * CC4 + lane + 64 * t];
            ad[t].x = fabsf(xi[t].x - xj.x);
            ad[t].y = fabsf(xi[t].y - xj.y);
            ad[t].z = fabsf(xi[t].z - xj.z);
            ad[t].w = fabsf(xi[t].w - xj.w);
            s += ad[t].x + ad[t].y + ad[t].z + ad[t].w;
        }
        #pragma unroll
        for (int off = 32; off > 0; off >>= 1) s += __shfl_xor(s, off, 64);
        const float thr = s * (MARGIN / CC);
        #pragma unroll
        for (int t = 0; t < 4; ++t) {
            c4[t].x += (ad[t].x < thr) ? 1.f : 0.f;
            c4[t].y += (ad[t].y < thr) ? 1.f : 0.f;
            c4[t].z += (ad[t].z < thr) ? 1.f : 0.f;
            c4[t].w += (ad[t].w < thr) ? 1.f : 0.f;
        }
    }
    float4* m4 = (float4*)mcsq;
    #pragma unroll
    for (int t = 0; t < 4; ++t) {
        float4 o;
        o.x = c4[t].x * c4[t].x;
        o.y = c4[t].y * c4[t].y;
        o.z = c4[t].z * c4[t].z;
        o.w = c4[t].w * c4[t].w;
        m4[(long)i * CC4 + lane + 64 * t] = o;
    }
}

__global__ __launch_bounds__(256) void pass1_kernel(
    const float* __restrict__ x, float* __restrict__ S_part)
{
    __shared__ float xs[64 * LDST];
    const int b  = blockIdx.x;
    const int cc = b & 7;
    const int jt = (b >> 3) & 7;
    const int it = b >> 6;
    const int l  = threadIdx.x;

    const float4* x4 = (const float4*)x;
    #pragma unroll
    for (int k = 0; k < 8; ++k) {
        const int idx = l + 256 * k;
        const int row = idx >> 5;
        const int c4  = idx & 31;
        const int grow = (row < 32) ? (it * 32 + row) : (jt * 32 + row - 32);
        *(float4*)&xs[row * LDST + c4 * 4] = x4[grow * CC4 + cc * 32 + c4];
    }
    __syncthreads();

    const int li = l >> 4, lj = l & 15;
    const float4* pi0 = (const float4*)&xs[(2 * li) * LDST];
    const float4* pi1 = (const float4*)&xs[(2 * li + 1) * LDST];
    const float4* pj0 = (const float4*)&xs[(32 + 2 * lj) * LDST];
    const float4* pj1 = (const float4*)&xs[(32 + 2 * lj + 1) * LDST];
    float s00 = 0.f, s01 = 0.f, s10 = 0.f, s11 = 0.f;
    #pragma unroll 8
    for (int q = 0; q < 32; ++q) {
        const float4 a0 = pi0[q], a1 = pi1[q], b0 = pj0[q], b1 = pj1[q];
        s00 += fabsf(a0.x - b0.x) + fabsf(a0.y - b0.y) + fabsf(a0.z - b0.z) + fabsf(a0.w - b0.w);
        s01 += fabsf(a0.x - b1.x) + fabsf(a0.y - b1.y) + fabsf(a0.z - b1.z) + fabsf(a0.w - b1.w);
        s10 += fabsf(a1.x - b0.x) + fabsf(a1.y - b0.y) + fabsf(a1.z - b0.z) + fabsf(a1.w - b0.w);
        s11 += fabsf(a1.x - b1.x) + fabsf(a1.y - b1.y) + fabsf(a1.z - b1.z) + fabsf(a1.w - b1.w);
    }
    const int gi0 = it * 32 + 2 * li, gj0 = jt * 32 + 2 * lj;
    float* Sp = S_part + cc * (BB * BB);
    Sp[gi0 * BB + gj0]           = s00;
    Sp[gi0 * BB + gj0 + 1]       = s01;
    Sp[(gi0 + 1) * BB + gj0]     = s10;
    Sp[(gi0 + 1) * BB + gj0 + 1] = s11;
}

__global__ __launch_bounds__(256) void thr_kernel(
    const float* __restrict__ S_part, float* __restrict__ THR)
{
    const int g = blockIdx.x * 256 + threadIdx.x;
    float s = 0.f;
    #pragma unroll
    for (int cc = 0; cc < NSL; ++cc) s += S_part[cc * (BB * BB) + g];
    THR[g] = s * (MARGIN / CC);
}

__global__ __launch_bounds__(256) void pass2_kernel(
    const float* __restrict__ x, const float* __restrict__ mcsq,
    const float* __restrict__ THR,
    float* __restrict__ IDS_part, float* __restrict__ MD_part)
{
    __shared__ float xs[64 * LDST];
    __shared__ float ms[64 * LDST];
    const int b  = blockIdx.x;
    const int cc = b & 7;
    const int jt = (b >> 3) & 7;
    const int it = b >> 6;
    const int l  = threadIdx.x;

    const float4* x4 = (const float4*)x;
    const float4* m4 = (const float4*)mcsq;
    #pragma unroll
    for (int k = 0; k < 8; ++k) {
        const int idx = l + 256 * k;
        const int row = idx >> 5;
        const int c4  = idx & 31;
        const int grow = (row < 32) ? (it * 32 + row) : (jt * 32 + row - 32);
        *(float4*)&xs[row * LDST + c4 * 4] = x4[grow * CC4 + cc * 32 + c4];
        *(float4*)&ms[row * LDST + c4 * 4] = m4[grow * CC4 + cc * 32 + c4];
    }
    const int li = l >> 4, lj = l & 15;
    const int gi0 = it * 32 + 2 * li, gj0 = jt * 32 + 2 * lj;
    const float t00 = THR[gi0 * BB + gj0];
    const float t01 = THR[gi0 * BB + gj0 + 1];
    const float t10 = THR[(gi0 + 1) * BB + gj0];
    const float t11 = THR[(gi0 + 1) * BB + gj0 + 1];
    __syncthreads();

    const float4* pi0 = (const float4*)&xs[(2 * li) * LDST];
    const float4* pi1 = (const float4*)&xs[(2 * li + 1) * LDST];
    const float4* pj0 = (const float4*)&xs[(32 + 2 * lj) * LDST];
    const float4* pj1 = (const float4*)&xs[(32 + 2 * lj + 1) * LDST];
    const float4* qi0 = (const float4*)&ms[(2 * li) * LDST];
    const float4* qi1 = (const float4*)&ms[(2 * li + 1) * LDST];
    const float4* qj0 = (const float4*)&ms[(32 + 2 * lj) * LDST];
    const float4* qj1 = (const float4*)&ms[(32 + 2 * lj + 1) * LDST];

    float i00 = 0.f, i01 = 0.f, i10 = 0.f, i11 = 0.f;
    float m00 = 0.f, m01 = 0.f, m10 = 0.f, m11 = 0.f;
    #pragma unroll 4
    for (int q = 0; q < 32; ++q) {
        const float4 a0 = pi0[q], a1 = pi1[q], b0 = pj0[q], b1 = pj1[q];
        const float4 wa0 = qi0[q], wa1 = qi1[q], wb0 = qj0[q], wb1 = qj1[q];
        #pragma unroll
        for (int u = 0; u < 4; ++u) {
            const float xa0 = (&a0.x)[u], xa1 = (&a1.x)[u];
            const float xb0 = (&b0.x)[u], xb1 = (&b1.x)[u];
            const float va0 = (&wa0.x)[u], va1 = (&wa1.x)[u];
            const float vb0 = (&wb0.x)[u], vb1 = (&wb1.x)[u];
            float d, qq;
            d = xa0 - xb0; qq = d * d; i00 += (fabsf(d) < t00) ? qq : 0.f; m00 += qq * va0 * vb0;
            d = xa0 - xb1; qq = d * d; i01 += (fabsf(d) < t01) ? qq : 0.f; m01 += qq * va0 * vb1;
            d = xa1 - xb0; qq = d * d; i10 += (fabsf(d) < t10) ? qq : 0.f; m10 += qq * va1 * vb0;
            d = xa1 - xb1; qq = d * d; i11 += (fabsf(d) < t11) ? qq : 0.f; m11 += qq * va1 * vb1;
        }
    }
    float* Ip = IDS_part + cc * (BB * BB);
    float* Mp = MD_part  + cc * (BB * BB);
    Ip[gi0 * BB + gj0]           = i00;
    Ip[gi0 * BB + gj0 + 1]       = i01;
    Ip[(gi0 + 1) * BB + gj0]     = i10;
    Ip[(gi0 + 1) * BB + gj0 + 1] = i11;
    Mp[gi0 * BB + gj0]           = m00;
    Mp[gi0 * BB + gj0 + 1]       = m01;
    Mp[(gi0 + 1) * BB + gj0]     = m10;
    Mp[(gi0 + 1) * BB + gj0 + 1] = m11;
}

__global__ __launch_bounds__(64) void final_kernel(
    const float* __restrict__ IDS_part, const float* __restrict__ MD_part,
    const int* __restrict__ targets,
    float* __restrict__ acc, unsigned int* __restrict__ cnt_g,
    float* __restrict__ out)
{
    const int i = blockIdx.x;
    const int lane = threadIdx.x;
    const int ti = targets[i];

    float4 idv = make_float4(0.f, 0.f, 0.f, 0.f);
    float4 mdv = make_float4(0.f, 0.f, 0.f, 0.f);
    #pragma unroll
    for (int cc = 0; cc < NSL; ++cc) {
        const float4 a = ((const float4*)(IDS_part + cc * (BB * BB) + i * BB))[lane];
        const float4 b = ((const float4*)(MD_part  + cc * (BB * BB) + i * BB))[lane];
        idv.x += a.x; idv.y += a.y; idv.z += a.z; idv.w += a.w;
        mdv.x += b.x; mdv.y += b.y; mdv.z += b.z; mdv.w += b.w;
    }
    const int4 tjv = ((const int4*)targets)[lane];

    float mx, mn;
    mx =           sqrtf(fmaxf(mdv.x, 1e-12f));
    mx = fmaxf(mx, sqrtf(fmaxf(mdv.y, 1e-12f)));
    mx = fmaxf(mx, sqrtf(fmaxf(mdv.z, 1e-12f)));
    mx = fmaxf(mx, sqrtf(fmaxf(mdv.w, 1e-12f)));
    mn =           (tjv.x != ti) ? sqrtf(fmaxf(idv.x, 1e-12f)) : INFINITY;
    mn = fminf(mn, (tjv.y != ti) ? sqrtf(fmaxf(idv.y, 1e-12f)) : INFINITY);
    mn = fminf(mn, (tjv.z != ti) ? sqrtf(fmaxf(idv.z, 1e-12f)) : INFINITY);
    mn = fminf(mn, (tjv.w != ti) ? sqrtf(fmaxf(idv.w, 1e-12f)) : INFINITY);

    #pragma unroll
    for (int off = 32; off > 0; off >>= 1) {
        mx = fmaxf(mx, __shfl_xor(mx, off, 64));
        mn = fminf(mn, __shfl_xor(mn, off, 64));
    }
    if (lane == 0) {
        const float per = fmaxf(mx * 10.f - mn, 0.f);
        atomicAdd(acc, per * (1.0f / BB));
        __threadfence();
        const unsigned int old = atomicAdd(cnt_g, 1u);
        if (old == BB - 1) {
            __threadfence();
            out[0] = atomicAdd(acc, 0.0f);
        }
    }
}

extern "C" void kernel_launch(void* const* d_in, const int* in_sizes, int n_in,
                              void* d_out, int out_size, void* d_ws, size_t ws_size,
                              hipStream_t stream)
{
    const float* x       = (const float*)d_in[0];
    const int*   targets = (const int*)d_in[1];
    const int*   subs    = (const int*)d_in[2];
    const int*   m_count = (const int*)d_in[3];
    float* out  = (float*)d_out;

    float* mcsq     = (float*)d_ws;                    // 256*1024
    float* S_part   = mcsq     + (long)BB * CC;        // 8*65536
    float* THR      = S_part   + NSL * BB * BB;        // 65536 (fallback only)
    float* IDS_part = THR      + BB * BB;              // 8*65536
    float* MD_part  = IDS_part + NSL * BB * BB;        // 8*65536
    float* acc      = MD_part  + NSL * BB * BB;        // 1
    unsigned int* cnt_g = (unsigned int*)(acc + 1);

    // Cooperative path: precheck co-residency, then launch and verify.
    bool coop_ok = false;
    int maxB = 0;
    if (hipOccupancyMaxActiveBlocksPerMultiprocessor(&maxB, mega_kernel, 256, 0)
            == hipSuccess && maxB >= 2) {
        void* args[] = {(void*)&x, (void*)&targets, (void*)&subs, (void*)&m_count,
                        (void*)&mcsq, (void*)&S_part, (void*)&IDS_part, (void*)&MD_part,
                        (void*)&acc, (void*)&cnt_g, (void*)&out};
        if (hipLaunchCooperativeKernel((const void*)mega_kernel, dim3(512),
                                       dim3(256), args, 0, stream) == hipSuccess)
            coop_ok = true;
    }
    if (!coop_ok) {
        // Fallback: R7 chain (known correct).
        mcsq_kernel <<<BB,  64,  0, stream>>>(x, targets, subs, m_count, mcsq, acc, cnt_g);
        pass1_kernel<<<512, 256, 0, stream>>>(x, S_part);
        thr_kernel  <<<256, 256, 0, stream>>>(S_part, THR);
        pass2_kernel<<<512, 256, 0, stream>>>(x, mcsq, THR, IDS_part, MD_part);
        final_kernel<<<BB,  64,  0, stream>>>(IDS_part, MD_part, targets, acc, cnt_g, out);
    }
}

// Round 10
// 98.374 us; speedup vs baseline: 2.0437x; 2.0437x over previous
//
#include <hip/hip_runtime.h>
#include <math.h>

#define BB 256       // batch
#define CC 1024      // channels
#define CC4 (CC/4)   // row length in float4
#define MARGIN 0.5f
#define NSL1 8       // pass1 c-slices (128 c each)
#define NSL2 16      // pass2 c-slices (64 c each)
#define LDST 132     // pass1 LDS row stride (floats)
#define LDSM 68      // pass2 LDS row stride (floats)

// ws (floats): mcsq[256*1024] | S_part[8*65536] | IDS_part[16*65536] |
//              MD_part[16*65536] | acc | cnt

// ---------------------------------------------------------------------------
// K1: S_part slices + mcsq + acc/cnt init.  Grid 512 = 8cc x 8jt x 8it.
// Block = 32i x 32j x 128c, 2x2 pairs/lane, LDS-staged, no atomics.
// Blocks 448..511 additionally compute mcsq (1 row per wave).
// ---------------------------------------------------------------------------
__global__ __launch_bounds__(256) void pass1_kernel(
    const float* __restrict__ x, const int* __restrict__ targets,
    const int* __restrict__ subs, const int* __restrict__ m_count_p,
    float* __restrict__ mcsq, float* __restrict__ S_part,
    float* __restrict__ acc, unsigned int* __restrict__ cnt_g)
{
    __shared__ float xs[64 * LDST];
    const int b  = blockIdx.x;
    const int cc = b & 7;
    const int jt = (b >> 3) & 7;
    const int it = b >> 6;
    const int l  = threadIdx.x;
    if (b == 0 && l == 0) { *acc = 0.f; *cnt_g = 0u; }

    const float4* x4 = (const float4*)x;
    #pragma unroll
    for (int k = 0; k < 8; ++k) {
        const int idx = l + 256 * k;       // 0..2047
        const int row = idx >> 5;          // 0..63
        const int c4  = idx & 31;
        const int grow = (row < 32) ? (it * 32 + row) : (jt * 32 + row - 32);
        *(float4*)&xs[row * LDST + c4 * 4] = x4[grow * CC4 + cc * 32 + c4];
    }
    __syncthreads();

    const int li = l >> 4, lj = l & 15;
    const float4* pi0 = (const float4*)&xs[(2 * li) * LDST];
    const float4* pi1 = (const float4*)&xs[(2 * li + 1) * LDST];
    const float4* pj0 = (const float4*)&xs[(32 + 2 * lj) * LDST];
    const float4* pj1 = (const float4*)&xs[(32 + 2 * lj + 1) * LDST];
    float s00 = 0.f, s01 = 0.f, s10 = 0.f, s11 = 0.f;
    #pragma unroll 8
    for (int q = 0; q < 32; ++q) {
        const float4 a0 = pi0[q], a1 = pi1[q], b0 = pj0[q], b1 = pj1[q];
        s00 += fabsf(a0.x - b0.x) + fabsf(a0.y - b0.y) + fabsf(a0.z - b0.z) + fabsf(a0.w - b0.w);
        s01 += fabsf(a0.x - b1.x) + fabsf(a0.y - b1.y) + fabsf(a0.z - b1.z) + fabsf(a0.w - b1.w);
        s10 += fabsf(a1.x - b0.x) + fabsf(a1.y - b0.y) + fabsf(a1.z - b0.z) + fabsf(a1.w - b0.w);
        s11 += fabsf(a1.x - b1.x) + fabsf(a1.y - b1.y) + fabsf(a1.z - b1.z) + fabsf(a1.w - b1.w);
    }
    const int gi0 = it * 32 + 2 * li, gj0 = jt * 32 + 2 * lj;
    float* Sp = S_part + cc * (BB * BB);
    Sp[gi0 * BB + gj0]           = s00;
    Sp[gi0 * BB + gj0 + 1]       = s01;
    Sp[(gi0 + 1) * BB + gj0]     = s10;
    Sp[(gi0 + 1) * BB + gj0 + 1] = s11;

    // mcsq on blocks 448..511: row i = (b-448)*4 + wave
    if (b >= 448) {
        const int lane = l & 63;
        const int i = (b - 448) * 4 + (l >> 6);
        const int ti = targets[i], si = subs[i];
        int mc = *m_count_p;
        if (mc > 8) mc = 8;

        unsigned long long masks[4];
        #pragma unroll
        for (int q = 0; q < 4; ++q) {
            const int j = q * 64 + lane;
            masks[q] = __ballot(targets[j] == ti && subs[j] == si);
        }
        int idx[8];
        int cnt = 0;
        for (int q = 0; q < 4 && cnt < mc; ++q) {
            unsigned long long m = masks[q];
            while (m && cnt < mc) {
                const int bb2 = __ffsll(m) - 1;
                idx[cnt++] = q * 64 + bb2;
                m &= m - 1;
            }
        }
        for (int q = 0; q < 4 && cnt < mc; ++q) {   // stable-argsort padding
            unsigned long long m = ~masks[q];
            while (m && cnt < mc) {
                const int bb2 = __ffsll(m) - 1;
                idx[cnt++] = q * 64 + bb2;
                m &= m - 1;
            }
        }

        float4 xi[4];
        #pragma unroll
        for (int t = 0; t < 4; ++t) xi[t] = x4[(long)i * CC4 + lane + 64 * t];
        float4 c4v[4];
        #pragma unroll
        for (int t = 0; t < 4; ++t) c4v[t] = make_float4(0.f, 0.f, 0.f, 0.f);

        for (int k = 0; k < cnt; ++k) {
            float4 ad[4];
            float s = 0.f;
            #pragma unroll
            for (int t = 0; t < 4; ++t) {
                const float4 xj = x4[(long)idx[k] * CC4 + lane + 64 * t];
                ad[t].x = fabsf(xi[t].x - xj.x);
                ad[t].y = fabsf(xi[t].y - xj.y);
                ad[t].z = fabsf(xi[t].z - xj.z);
                ad[t].w = fabsf(xi[t].w - xj.w);
                s += ad[t].x + ad[t].y + ad[t].z + ad[t].w;
            }
            #pragma unroll
            for (int off = 32; off > 0; off >>= 1) s += __shfl_xor(s, off, 64);
            const float thr = s * (MARGIN / CC);
            #pragma unroll
            for (int t = 0; t < 4; ++t) {
                c4v[t].x += (ad[t].x < thr) ? 1.f : 0.f;
                c4v[t].y += (ad[t].y < thr) ? 1.f : 0.f;
                c4v[t].z += (ad[t].z < thr) ? 1.f : 0.f;
                c4v[t].w += (ad[t].w < thr) ? 1.f : 0.f;
            }
        }
        float4* mout = (float4*)mcsq;
        #pragma unroll
        for (int t = 0; t < 4; ++t) {
            float4 o;
            o.x = c4v[t].x * c4v[t].x;
            o.y = c4v[t].y * c4v[t].y;
            o.z = c4v[t].z * c4v[t].z;
            o.w = c4v[t].w * c4v[t].w;
            mout[(long)i * CC4 + lane + 64 * t] = o;
        }
    }
}

// ---------------------------------------------------------------------------
// K2: IDS/MD slices. Grid 1024 = 16cc x 8jt x 8it. Block = 32i x 32j x 64c,
// 34.8 KB LDS -> 4 blocks/CU. thr folded inline from the 8 S_part slices.
// ---------------------------------------------------------------------------
__global__ __launch_bounds__(256) void pass2_kernel(
    const float* __restrict__ x, const float* __restrict__ mcsq,
    const float* __restrict__ S_part,
    float* __restrict__ IDS_part, float* __restrict__ MD_part)
{
    __shared__ float xs[64 * LDSM];
    __shared__ float ms[64 * LDSM];
    const int b  = blockIdx.x;
    const int cc = b & 15;         // 64-c chunk
    const int jt = (b >> 4) & 7;
    const int it = b >> 7;
    const int l  = threadIdx.x;

    const float4* x4 = (const float4*)x;
    const float4* m4 = (const float4*)mcsq;
    #pragma unroll
    for (int k = 0; k < 4; ++k) {
        const int idx = l + 256 * k;       // 0..1023
        const int row = idx >> 4;          // 0..63
        const int c4  = idx & 15;
        const int grow = (row < 32) ? (it * 32 + row) : (jt * 32 + row - 32);
        *(float4*)&xs[row * LDSM + c4 * 4] = x4[grow * CC4 + cc * 16 + c4];
        *(float4*)&ms[row * LDSM + c4 * 4] = m4[grow * CC4 + cc * 16 + c4];
    }

    const int li = l >> 4, lj = l & 15;
    const int gi0 = it * 32 + 2 * li, gj0 = jt * 32 + 2 * lj;
    float t00 = 0.f, t01 = 0.f, t10 = 0.f, t11 = 0.f;
    #pragma unroll
    for (int s = 0; s < NSL1; ++s) {
        const float* Sp = S_part + s * (BB * BB);
        t00 += Sp[gi0 * BB + gj0];
        t01 += Sp[gi0 * BB + gj0 + 1];
        t10 += Sp[(gi0 + 1) * BB + gj0];
        t11 += Sp[(gi0 + 1) * BB + gj0 + 1];
    }
    t00 *= (MARGIN / CC); t01 *= (MARGIN / CC);
    t10 *= (MARGIN / CC); t11 *= (MARGIN / CC);
    __syncthreads();

    const float4* pi0 = (const float4*)&xs[(2 * li) * LDSM];
    const float4* pi1 = (const float4*)&xs[(2 * li + 1) * LDSM];
    const float4* pj0 = (const float4*)&xs[(32 + 2 * lj) * LDSM];
    const float4* pj1 = (const float4*)&xs[(32 + 2 * lj + 1) * LDSM];
    const float4* qi0 = (const float4*)&ms[(2 * li) * LDSM];
    const float4* qi1 = (const float4*)&ms[(2 * li + 1) * LDSM];
    const float4* qj0 = (const float4*)&ms[(32 + 2 * lj) * LDSM];
    const float4* qj1 = (const float4*)&ms[(32 + 2 * lj + 1) * LDSM];

    float i00 = 0.f, i01 = 0.f, i10 = 0.f, i11 = 0.f;
    float m00 = 0.f, m01 = 0.f, m10 = 0.f, m11 = 0.f;
    #pragma unroll 4
    for (int q = 0; q < 16; ++q) {
        const float4 a0 = pi0[q], a1 = pi1[q], b0 = pj0[q], b1 = pj1[q];
        const float4 wa0 = qi0[q], wa1 = qi1[q], wb0 = qj0[q], wb1 = qj1[q];
        #pragma unroll
        for (int u = 0; u < 4; ++u) {
            const float xa0 = (&a0.x)[u], xa1 = (&a1.x)[u];
            const float xb0 = (&b0.x)[u], xb1 = (&b1.x)[u];
            const float va0 = (&wa0.x)[u], va1 = (&wa1.x)[u];
            const float vb0 = (&wb0.x)[u], vb1 = (&wb1.x)[u];
            float d, qq;
            d = xa0 - xb0; qq = d * d; i00 += (fabsf(d) < t00) ? qq : 0.f; m00 += qq * va0 * vb0;
            d = xa0 - xb1; qq = d * d; i01 += (fabsf(d) < t01) ? qq : 0.f; m01 += qq * va0 * vb1;
            d = xa1 - xb0; qq = d * d; i10 += (fabsf(d) < t10) ? qq : 0.f; m10 += qq * va1 * vb0;
            d = xa1 - xb1; qq = d * d; i11 += (fabsf(d) < t11) ? qq : 0.f; m11 += qq * va1 * vb1;
        }
    }
    float* Ip = IDS_part + cc * (BB * BB);
    float* Mp = MD_part  + cc * (BB * BB);
    Ip[gi0 * BB + gj0]           = i00;
    Ip[gi0 * BB + gj0 + 1]       = i01;
    Ip[(gi0 + 1) * BB + gj0]     = i10;
    Ip[(gi0 + 1) * BB + gj0 + 1] = i11;
    Mp[gi0 * BB + gj0]           = m00;
    Mp[gi0 * BB + gj0 + 1]       = m01;
    Mp[(gi0 + 1) * BB + gj0]     = m10;
    Mp[(gi0 + 1) * BB + gj0 + 1] = m11;
}

// ---------------------------------------------------------------------------
// K3: final. One wave per row: fold 16 slices (float4), sqrt/max/min,
// butterfly, atomic mean; elected last wave publishes out[0].
// ---------------------------------------------------------------------------
__global__ __launch_bounds__(64) void final_kernel(
    const float* __restrict__ IDS_part, const float* __restrict__ MD_part,
    const int* __restrict__ targets,
    float* __restrict__ acc, unsigned int* __restrict__ cnt_g,
    float* __restrict__ out)
{
    const int i = blockIdx.x;
    const int lane = threadIdx.x;
    const int ti = targets[i];

    float4 idv = make_float4(0.f, 0.f, 0.f, 0.f);
    float4 mdv = make_float4(0.f, 0.f, 0.f, 0.f);
    #pragma unroll
    for (int cc = 0; cc < NSL2; ++cc) {
        const float4 a = ((const float4*)(IDS_part + cc * (BB * BB) + i * BB))[lane];
        const float4 c = ((const float4*)(MD_part  + cc * (BB * BB) + i * BB))[lane];
        idv.x += a.x; idv.y += a.y; idv.z += a.z; idv.w += a.w;
        mdv.x += c.x; mdv.y += c.y; mdv.z += c.z; mdv.w += c.w;
    }
    const int4 tjv = ((const int4*)targets)[lane];

    float mx, mn;
    mx =           sqrtf(fmaxf(mdv.x, 1e-12f));
    mx = fmaxf(mx, sqrtf(fmaxf(mdv.y, 1e-12f)));
    mx = fmaxf(mx, sqrtf(fmaxf(mdv.z, 1e-12f)));
    mx = fmaxf(mx, sqrtf(fmaxf(mdv.w, 1e-12f)));
    mn =           (tjv.x != ti) ? sqrtf(fmaxf(idv.x, 1e-12f)) : INFINITY;
    mn = fminf(mn, (tjv.y != ti) ? sqrtf(fmaxf(idv.y, 1e-12f)) : INFINITY);
    mn = fminf(mn, (tjv.z != ti) ? sqrtf(fmaxf(idv.z, 1e-12f)) : INFINITY);
    mn = fminf(mn, (tjv.w != ti) ? sqrtf(fmaxf(idv.w, 1e-12f)) : INFINITY);

    #pragma unroll
    for (int off = 32; off > 0; off >>= 1) {
        mx = fmaxf(mx, __shfl_xor(mx, off, 64));
        mn = fminf(mn, __shfl_xor(mn, off, 64));
    }
    if (lane == 0) {
        const float per = fmaxf(mx * 10.f - mn, 0.f);
        atomicAdd(acc, per * (1.0f / BB));
        __threadfence();
        const unsigned int old = atomicAdd(cnt_g, 1u);
        if (old == BB - 1) {
            __threadfence();
            out[0] = atomicAdd(acc, 0.0f);
        }
    }
}

extern "C" void kernel_launch(void* const* d_in, const int* in_sizes, int n_in,
                              void* d_out, int out_size, void* d_ws, size_t ws_size,
                              hipStream_t stream)
{
    const float* x       = (const float*)d_in[0];
    const int*   targets = (const int*)d_in[1];
    const int*   subs    = (const int*)d_in[2];
    const int*   m_count = (const int*)d_in[3];
    float* out  = (float*)d_out;

    float* mcsq     = (float*)d_ws;                    // 256*1024
    float* S_part   = mcsq     + (long)BB * CC;        // 8*65536
    float* IDS_part = S_part   + NSL1 * BB * BB;       // 16*65536
    float* MD_part  = IDS_part + NSL2 * BB * BB;       // 16*65536
    float* acc      = MD_part  + NSL2 * BB * BB;       // 1
    unsigned int* cnt_g = (unsigned int*)(acc + 1);

    pass1_kernel<<<512,  256, 0, stream>>>(x, targets, subs, m_count, mcsq,
                                           S_part, acc, cnt_g);
    pass2_kernel<<<1024, 256, 0, stream>>>(x, mcsq, S_part, IDS_part, MD_part);
    final_kernel<<<BB,   64,  0, stream>>>(IDS_part, MD_part, targets,
                                           acc, cnt_g, out);
}